// Round 18
// baseline (112.857 us; speedup 1.0000x reference)
//
#include <hip/hip_runtime.h>

// R32: P1 software pipeline. R31 post-mortem: scalarization gained only
// 1.8us (predicted 9-14) -> either R30's 80MB scratch was an x2-wrapper
// codegen artifact (visibility perturbs the measured kernel), or scratch
// was off critical path. P1 ~11.6us vs ~6 issue floor; remaining stall
// candidates = inter-task dependent-load latency (3 serial task bodies,
// each gated by 4 row-loads) + cold-x HBM read (L3 wiped by poison fill).
//   Change: peel interior loop (tasks tid / tid+1024 / tid+2048 if <868),
//   issue next task's 4 row-loads BEFORE computing current task's conv
//   (SSA named values only, rule #20). Loads hide under ~200 VALU of conv.
//   Risk: +16 live VGPR vs 64-cap @ (1024,8) -> spill = regression, revert.
// Everything else = R31 verbatim (passed 109.19us, absmax 0.0156).
// Pinned: (R14) no cross-block sync; (R18) occupancy-alone null; (R19)
// pixel-major hsu, k=tap*8+ch; (R20) fill ~43 unconditional; (R21/24)
// barrier count ~null; (R22/23) per-K-step B-frags; (R25-27) k_all 26.7 =
// P1 11.6 + P2 5.7 + fc 4.4 (+setup); (R28) setup->P1 LDS reads need
// barrier; (R29) fdot2 conv1; (R30/31) x2-visibility may perturb codegen;
// scalarization alone ~null -> stall source unproven.
// Predict: absmax 0.0156; total -> ~104-106. Null -> visibility+declare;
// regression -> spill, revert.

#define HS 58    // hsu row stride in pixels (16B each)
#define FS 72    // fsu row stride in f16 (144B; 36 u32 ≡ 4 mod 32)
#define FSW 36   // fsu row stride in u32

typedef _Float16 half2_t __attribute__((ext_vector_type(2)));
typedef __fp16 fp16r2 __attribute__((ext_vector_type(2)));  // cvt_pkrtz ret
typedef _Float16 f16x8 __attribute__((ext_vector_type(8)));
typedef float f32x4 __attribute__((ext_vector_type(4)));
typedef float f32x4u __attribute__((ext_vector_type(4), aligned(4)));

__device__ __forceinline__ unsigned pack_f16(float a, float b) {
  union { half2_t h; unsigned u; } z;
  z.h[0] = (_Float16)a;  // RNE
  z.h[1] = (_Float16)b;
  return z.u;
}

__device__ __forceinline__ half2_t pkrtz2(float a, float b) {
#if __has_builtin(__builtin_amdgcn_cvt_pkrtz)
  union { fp16r2 r; half2_t h; } z;
  z.r = __builtin_amdgcn_cvt_pkrtz(a, b);
  return z.h;
#else
  half2_t h;
  h[0] = (_Float16)a;
  h[1] = (_Float16)b;
  return h;
#endif
}

__device__ __forceinline__ half2_t as_h2(unsigned u) {
  union { unsigned u; half2_t h; } z;
  z.u = u;
  return z.h;
}

__device__ __forceinline__ f16x8 as_f16x8(uint4 u) {
  union { uint4 u; f16x8 f; } z;
  z.u = u;
  return z.f;
}

__device__ __forceinline__ float fdot2_(half2_t a, half2_t b, float c) {
#if __has_builtin(__builtin_amdgcn_fdot2)
  return __builtin_amdgcn_fdot2(a, b, c, false);
#else
  return c + (float)a[0] * (float)b[0] + (float)a[1] * (float)b[1];
#endif
}

// Guarded border-row load: returns the 4-tap row as an SSA value (no array).
__device__ __forceinline__ f32x4u brow(const float* __restrict__ xb, int iy,
                                       int ix0) {
  f32x4u r = {0.f, 0.f, 0.f, 0.f};
  if ((unsigned)iy < 112u) {
    const float* p = xb + iy * 112;
    r.x = ((unsigned)(ix0 + 0) < 112u) ? p[ix0 + 0] : 0.f;
    r.y = ((unsigned)(ix0 + 1) < 112u) ? p[ix0 + 1] : 0.f;
    r.z = ((unsigned)(ix0 + 2) < 112u) ? p[ix0 + 2] : 0.f;
    r.w = ((unsigned)(ix0 + 3) < 112u) ? p[ix0 + 3] : 0.f;
  }
  return r;
}

// conv1 8ch on a 4x4 window (rows BY VALUE -> registers, no scratch),
// 2x2 maxpool + bias + relu, packed to one uint4 (8 f16).
// wpl = LDS table of w1 tap-pairs (taps 0,1 per row), [ch*3+t].
__device__ __forceinline__ uint4 conv8v(f32x4u r0, f32x4u r1, f32x4u r2,
                                        f32x4u r3, const unsigned* wpl,
                                        const float* __restrict__ w1,
                                        const float* __restrict__ b1) {
  half2_t a0 = pkrtz2(r0.x, r0.y), c0 = pkrtz2(r0.y, r0.z);
  half2_t a1 = pkrtz2(r1.x, r1.y), c1 = pkrtz2(r1.y, r1.z);
  half2_t a2 = pkrtz2(r2.x, r2.y), c2 = pkrtz2(r2.y, r2.z);
  half2_t a3 = pkrtz2(r3.x, r3.y), c3 = pkrtz2(r3.y, r3.z);
  uint4 hw;
#pragma unroll
  for (int cp = 0; cp < 4; ++cp) {
    float hA = 0.f, hB = 0.f;
#pragma unroll
    for (int sub = 0; sub < 2; ++sub) {
      const int ch = 2 * cp + sub;
      half2_t w0 = as_h2(wpl[ch * 3 + 0]);
      half2_t w1p = as_h2(wpl[ch * 3 + 1]);
      half2_t w2p = as_h2(wpl[ch * 3 + 2]);
      float t0 = w1[ch * 9 + 2], t1 = w1[ch * 9 + 5], t2 = w1[ch * 9 + 8];
      float s00 = fdot2_(a2, w2p, fdot2_(a1, w1p, fdot2_(a0, w0, 0.f)));
      s00 = __builtin_fmaf(t0, r0.z, s00);
      s00 = __builtin_fmaf(t1, r1.z, s00);
      s00 = __builtin_fmaf(t2, r2.z, s00);
      float s01 = fdot2_(c2, w2p, fdot2_(c1, w1p, fdot2_(c0, w0, 0.f)));
      s01 = __builtin_fmaf(t0, r0.w, s01);
      s01 = __builtin_fmaf(t1, r1.w, s01);
      s01 = __builtin_fmaf(t2, r2.w, s01);
      float s10 = fdot2_(a3, w2p, fdot2_(a2, w1p, fdot2_(a1, w0, 0.f)));
      s10 = __builtin_fmaf(t0, r1.z, s10);
      s10 = __builtin_fmaf(t1, r2.z, s10);
      s10 = __builtin_fmaf(t2, r3.z, s10);
      float s11 = fdot2_(c3, w2p, fdot2_(c2, w1p, fdot2_(c1, w0, 0.f)));
      s11 = __builtin_fmaf(t0, r1.w, s11);
      s11 = __builtin_fmaf(t1, r2.w, s11);
      s11 = __builtin_fmaf(t2, r3.w, s11);
      float m = fmaxf(fmaxf(s00, s01), fmaxf(s10, s11));
      float h = fmaxf(m + b1[ch], 0.f);
      if (sub == 0) hA = h; else hB = h;
    }
    unsigned pk = pack_f16(hA, hB);
    if (cp == 0) hw.x = pk;
    else if (cp == 1) hw.y = pk;
    else if (cp == 2) hw.z = pk;
    else hw.w = pk;
  }
  return hw;
}

__global__ __launch_bounds__(1024, 8) void k_all(
    const float* __restrict__ x, const float* __restrict__ w1,
    const float* __restrict__ b1, const float* __restrict__ w2,
    const float* __restrict__ b2, const float* __restrict__ wp,
    const float* __restrict__ bp, const float* __restrict__ w_fc1,
    const float* __restrict__ b_fc1, const float* __restrict__ w_fc2,
    const float* __restrict__ b_fc2, float* __restrict__ out) {
  // hsu: [hr 0..57][hc 0..57][ch 0..7] f16; hr = pooled_row+1 (ring = zero)
  __shared__ __align__(16) unsigned hsu[HS * HS * 4];  // 53.8 KB
  __shared__ __align__(16) unsigned bwl[768];          // 3.0 KB [oc16][tap12][w4]
  __shared__ __align__(16) unsigned wpl[24];           // conv1 w-pairs [ch*3+t]
  __shared__ __align__(16) unsigned fsu[122 * FSW];    // 17.6 KB f16 K-major
  __shared__ __align__(16) float pfl[784];             // 3.1 KB
  __shared__ float h1s[64];
  const int tid = threadIdx.x;
  const int b = blockIdx.x;
  const int l = tid & 63;
  const int wv = __builtin_amdgcn_readfirstlane(tid >> 6);  // wave id 0..15
  const float* xb = x + (long)b * 12544;

  // ---- setup ----
  if (tid < 228) {  // zero the padding ring (P1 writes interior only)
    int i = tid, hr, hc;
    if (i < 58) { hr = 0; hc = i; }
    else if (i < 116) { hr = 57; hc = i - 58; }
    else if (i < 172) { hr = i - 115; hc = 0; }
    else { hr = i - 171; hc = 57; }
    *(uint4*)(hsu + (hr * HS + hc) * 4) = make_uint4(0u, 0u, 0u, 0u);
  }
  if (tid < 768) {  // conv2 weights: bwl[(oc*12+tap)*4+w]
    int t = tid, oc = t / 48, rem = t - oc * 48;
    int tap = rem >> 2, w = rem & 3;
    unsigned v = 0u;
    if (tap < 9)
      v = pack_f16(w2[(oc * 8 + 2 * w) * 9 + tap],
                   w2[(oc * 8 + 2 * w + 1) * 9 + tap]);
    bwl[t] = v;
  }
  if (tid >= 768 && tid < 792) {  // conv1 weight pairs (taps 0,1 per row)
    int t2 = tid - 768;
    int ch = t2 / 3, t = t2 - ch * 3;
    wpl[t2] = pack_f16(w1[ch * 9 + t * 3], w1[ch * 9 + t * 3 + 1]);
  }
  __syncthreads();  // BARRIER 0 — P1 reads wpl (R28 raced without this)

  // ---- P1: conv1+bias+relu+maxpool2, software-pipelined (SSA only) ----
  // Tasks: tid, tid+1024, and tid+2048 (if tid<868) = 2916 exactly once.
  // Next task's 4 row-loads are issued BEFORE the current conv (MLP).
  {
    const int tA = tid;
    int grA = 1 + tA / 54, gcA = 1 + tA % 54;
    const float* pA = xb + (2 * grA - 1) * 112 + (2 * gcA - 1);
    f32x4u A0 = *(const f32x4u*)(pA);
    f32x4u A1 = *(const f32x4u*)(pA + 112);
    f32x4u A2 = *(const f32x4u*)(pA + 224);
    f32x4u A3 = *(const f32x4u*)(pA + 336);

    const int tB = tid + 1024;  // always < 2916
    int grB = 1 + tB / 54, gcB = 1 + tB % 54;
    const float* pB = xb + (2 * grB - 1) * 112 + (2 * gcB - 1);
    f32x4u B0 = *(const f32x4u*)(pB);
    f32x4u B1 = *(const f32x4u*)(pB + 112);
    f32x4u B2 = *(const f32x4u*)(pB + 224);
    f32x4u B3 = *(const f32x4u*)(pB + 336);

    uint4 hA = conv8v(A0, A1, A2, A3, wpl, w1, b1);
    *(uint4*)(hsu + ((grA + 1) * HS + gcA + 1) * 4) = hA;

    const bool has3 = tid < 868;
    f32x4u C0 = {0.f, 0.f, 0.f, 0.f}, C1 = C0, C2 = C0, C3 = C0;
    int grC = 0, gcC = 0;
    if (has3) {
      const int tC = tid + 2048;
      grC = 1 + tC / 54; gcC = 1 + tC % 54;
      const float* pC = xb + (2 * grC - 1) * 112 + (2 * gcC - 1);
      C0 = *(const f32x4u*)(pC);
      C1 = *(const f32x4u*)(pC + 112);
      C2 = *(const f32x4u*)(pC + 224);
      C3 = *(const f32x4u*)(pC + 336);
    }

    uint4 hB = conv8v(B0, B1, B2, B3, wpl, w1, b1);
    *(uint4*)(hsu + ((grB + 1) * HS + gcB + 1) * 4) = hB;

    if (has3) {
      uint4 hC = conv8v(C0, C1, C2, C3, wpl, w1, b1);
      *(uint4*)(hsu + ((grC + 1) * HS + gcC + 1) * 4) = hC;
    }
  }
  // Border ring (220 pixels): tids 804..1023, guarded row builds (SSA).
  if (tid >= 804) {
    int i = tid - 804;  // 0..219
    int gr, gc;
    if (i < 56) { gr = 0; gc = i; }
    else if (i < 112) { gr = 55; gc = i - 56; }
    else if (i < 166) { gr = i - 111; gc = 0; }
    else { gr = i - 165; gc = 55; }
    int iy0 = 2 * gr - 1, ix0 = 2 * gc - 1;
    f32x4u r0 = brow(xb, iy0 + 0, ix0);
    f32x4u r1 = brow(xb, iy0 + 1, ix0);
    f32x4u r2 = brow(xb, iy0 + 2, ix0);
    f32x4u r3 = brow(xb, iy0 + 3, ix0);
    uint4 hw = conv8v(r0, r1, r2, r3, wpl, w1, b1);
    *(uint4*)(hsu + ((gr + 1) * HS + gc + 1) * 4) = hw;
  }
  __syncthreads();  // BARRIER 1

  // ---- P2: conv2+pool+relu via MFMA; wave-local (R24 verbatim) ----
  {
    const int q = l >> 4;       // k-quarter / f-pixel role (a=q>>1, b=q&1)
    const int oc = l & 15;      // also: patch-row-in-window for projection
    const int yoff = 2 * ((l >> 3) & 1) + ((l >> 1) & 1);  // 2a+dy
    const int xoff = 2 * ((l >> 2) & 1) + (l & 1);         // 2b+dx
    int poff[3];
#pragma unroll
    for (int kk = 0; kk < 3; ++kk) {
      int t = kk * 4 + q;
      int tt = t < 9 ? t : 8;  // dead taps alias tap 8 (B there is zero)
      int ty = tt / 3, tx = tt - ty * 3;
      poff[kk] = ((yoff + ty) * HS + xoff + tx) * 4;  // u32 units
    }
    uint4 bu0 = *(const uint4*)(bwl + (oc * 12 + 0 + q) * 4);
    uint4 bu1 = *(const uint4*)(bwl + (oc * 12 + 4 + q) * 4);
    uint4 bu2 = *(const uint4*)(bwl + (oc * 12 + 8 + q) * 4);
    const float b2v = b2[oc];

    // Projection B-frags: MFMA#1 wp[oc][q*8+j]; MFMA#2 wp[oc][32+q*8+j].
    f16x8 wpf0 = {}, wpf1 = {};
    float bpj = 0.f;
    if (oc < 4) {
      const float* wr = wp + oc * 64 + q * 8;
      float4 wa = *(const float4*)(wr);
      float4 wb = *(const float4*)(wr + 4);
      float4 wc = *(const float4*)(wr + 32);
      float4 wd = *(const float4*)(wr + 36);
      union { unsigned u[4]; f16x8 v; } u0, u1;
      u0.u[0] = pack_f16(wa.x, wa.y);
      u0.u[1] = pack_f16(wa.z, wa.w);
      u0.u[2] = pack_f16(wb.x, wb.y);
      u0.u[3] = pack_f16(wb.z, wb.w);
      u1.u[0] = pack_f16(wc.x, wc.y);
      u1.u[1] = pack_f16(wc.z, wc.w);
      u1.u[2] = pack_f16(wd.x, wd.y);
      u1.u[3] = pack_f16(wd.z, wd.w);
      wpf0 = u0.v;
      wpf1 = u1.v;
      bpj = bp[oc];
    }

    _Float16* fsh = (_Float16*)fsu;
    const int NP = (wv < 4) ? 13 : 12;              // patches owned (contig)
    const int G0 = (wv < 4) ? 13 * wv : 12 * wv + 4;
    const int RW = 7 * wv;                          // private fsu row base
    const int npA = (NP + 1) >> 1;

    for (int hlf = 0; hlf < 2; ++hlf) {
      const int np = hlf ? NP - npA : npA;          // 7|6 then 6
      const int g0 = hlf ? G0 + npA : G0;
      for (int i = 0; i < np; ++i) {
        int p = g0 + i;
        int py = p / 14, px = p - py * 14;
        int pb = (4 * py * HS + 4 * px) * 4;  // u32 offset of patch origin
        uint4 a0u = *(const uint4*)(hsu + pb + poff[0]);
        uint4 a1u = *(const uint4*)(hsu + pb + poff[1]);
        uint4 a2u = *(const uint4*)(hsu + pb + poff[2]);
        f32x4 acc = {0.f, 0.f, 0.f, 0.f};
        acc = __builtin_amdgcn_mfma_f32_16x16x32_f16(as_f16x8(a0u), as_f16x8(bu0), acc, 0, 0, 0);
        acc = __builtin_amdgcn_mfma_f32_16x16x32_f16(as_f16x8(a1u), as_f16x8(bu1), acc, 0, 0, 0);
        acc = __builtin_amdgcn_mfma_f32_16x16x32_f16(as_f16x8(a2u), as_f16x8(bu2), acc, 0, 0, 0);
        float mx = fmaxf(fmaxf(acc[0], acc[1]), fmaxf(acc[2], acc[3]));
        float fv = fmaxf(mx + b2v, 0.f);  // f[oc][f-pixel q] of patch p
        fsh[(RW + i) * FS + oc * 4 + q] = (_Float16)fv;
      }
      // FENCE: writes via _Float16*, reads via unsigned* (TBAA no-alias).
      asm volatile("s_waitcnt lgkmcnt(0)" ::: "memory");
      __builtin_amdgcn_sched_barrier(0);
      const unsigned* ar = fsu + (RW + oc) * FSW + q * 4;
      uint4 pa0 = *(const uint4*)(ar);        // k 0..31 slice
      uint4 pa1 = *(const uint4*)(ar + 16);   // k 32..63 slice
      f32x4 pc = {0.f, 0.f, 0.f, 0.f};
      pc = __builtin_amdgcn_mfma_f32_16x16x32_f16(as_f16x8(pa0), wpf0, pc, 0, 0, 0);
      pc = __builtin_amdgcn_mfma_f32_16x16x32_f16(as_f16x8(pa1), wpf1, pc, 0, 0, 0);
      if (oc < 4) {
#pragma unroll
        for (int i2 = 0; i2 < 4; ++i2) {
          int prow = q * 4 + i2;  // C row = patch within window
          if (prow < np) pfl[(g0 + prow) * 4 + oc] = pc[i2] + bpj;
        }
      }
      asm volatile("" ::: "memory");  // WAR: next half's writes stay below
    }
  }
  __syncthreads();  // BARRIER 2

  // ---- fc1: thread (j = tid>>4, q16 = tid&15); 16-way K-split ----
  {
    int j = tid >> 4, q16 = tid & 15;
    const float* wrow = w_fc1 + j * 784;
    float acc = 0.f;
    for (int lp = q16; lp < 196; lp += 16) {
      float4 w4 = *(const float4*)(wrow + lp * 4);
      float4 p4 = *(const float4*)(pfl + lp * 4);
      acc += w4.x * p4.x + w4.y * p4.y + w4.z * p4.z + w4.w * p4.w;
    }
    acc += __shfl_down(acc, 8, 16);
    acc += __shfl_down(acc, 4, 16);
    acc += __shfl_down(acc, 2, 16);
    acc += __shfl_down(acc, 1, 16);
    if (q16 == 0) h1s[j] = fmaxf(acc + b_fc1[j], 0.f);
  }
  __syncthreads();  // BARRIER 3

  // ---- fc2 + log_softmax: wave 0 only ----
  if (wv == 0) {
    float h = h1s[l];
    float lg[10];
#pragma unroll
    for (int o = 0; o < 10; ++o) {
      float t = h * w_fc2[o * 64 + l];
#pragma unroll
      for (int off = 32; off; off >>= 1) t += __shfl_xor(t, off);
      lg[o] = t + b_fc2[o];  // every lane holds all 10 logits
    }
    float mx = lg[0];
#pragma unroll
    for (int o = 1; o < 10; ++o) mx = fmaxf(mx, lg[o]);
    float se = 0.f;
#pragma unroll
    for (int o = 0; o < 10; ++o) se += __expf(lg[o] - mx);
    float ls = mx + __logf(se);
#pragma unroll
    for (int o = 0; o < 10; ++o)  // static-index stores (no scratch)
      if (l == o) out[b * 10 + o] = lg[o] - ls;
  }
}

extern "C" void kernel_launch(void* const* d_in, const int* in_sizes, int n_in,
                              void* d_out, int out_size, void* d_ws, size_t ws_size,
                              hipStream_t stream) {
  const float* x = (const float*)d_in[0];
  const float* w1 = (const float*)d_in[1];
  const float* b1 = (const float*)d_in[2];
  const float* w2 = (const float*)d_in[3];
  const float* b2 = (const float*)d_in[4];
  const float* wp = (const float*)d_in[5];
  const float* bp = (const float*)d_in[6];
  const float* wf1 = (const float*)d_in[7];
  const float* bf1 = (const float*)d_in[8];
  const float* wf2 = (const float*)d_in[9];
  const float* bf2 = (const float*)d_in[10];
  (void)d_ws; (void)ws_size;  // workspace unused

  k_all<<<dim3(512), 1024, 0, stream>>>(x, w1, b1, w2, b2, wp, bp, wf1, bf1,
                                        wf2, bf2, (float*)d_out);
}

// Round 19
// 107.239 us; speedup vs baseline: 1.0524x; 1.0524x over previous
//
#include <hip/hip_runtime.h>

// R33 = R31 VERBATIM (lock-in revert). R32's software pipeline regressed
// 109.19 -> 112.86 (+16 live VGPR vs 64-cap @ (1024,8) -> spill/serialize;
// pre-committed rule: regression -> revert). R31 is the session best.
// FINAL STRUCTURAL ACCOUNTING (R25-32 measurements):
//   total 109 = harness 82 (poison fill 43 [R20: runs even with d_ws
//   unused] + launch/graph overhead ~39 [R25-27 multi-launch algebra])
//             + k_all ~27 (P1 11.6 vs ~6 floor; P2 5.7; fc 4.4; setup 1.5).
//   P1's residual ~2x multiplier survived scratch-elimination (R31, -1.8)
//   and software-pipelining (R32, regression); remaining upside ~5us (4.5%)
//   with demonstrated downside risk -> lock in.
// Session: 120.0 -> 109.2 us. Key lessons pinned:
//   (R19) LDS layout s.t. MFMA A-frag = one b128; (R20) single-kernel,
//   no-ws beats split kernels; (R22/23) split-K MFMA needs per-K B-frags;
//   (R28) setup->P1 LDS-product reads need a barrier; (R29) fdot2 halves
//   conv1 issue; (R30) x2-visibility wrappers perturb codegen — measure
//   via duration ablation instead; (R31) SSA-only locals (rule #20).

#define HS 58    // hsu row stride in pixels (16B each)
#define FS 72    // fsu row stride in f16 (144B; 36 u32 ≡ 4 mod 32)
#define FSW 36   // fsu row stride in u32

typedef _Float16 half2_t __attribute__((ext_vector_type(2)));
typedef __fp16 fp16r2 __attribute__((ext_vector_type(2)));  // cvt_pkrtz ret
typedef _Float16 f16x8 __attribute__((ext_vector_type(8)));
typedef float f32x4 __attribute__((ext_vector_type(4)));
typedef float f32x4u __attribute__((ext_vector_type(4), aligned(4)));

__device__ __forceinline__ unsigned pack_f16(float a, float b) {
  union { half2_t h; unsigned u; } z;
  z.h[0] = (_Float16)a;  // RNE
  z.h[1] = (_Float16)b;
  return z.u;
}

__device__ __forceinline__ half2_t pkrtz2(float a, float b) {
#if __has_builtin(__builtin_amdgcn_cvt_pkrtz)
  union { fp16r2 r; half2_t h; } z;
  z.r = __builtin_amdgcn_cvt_pkrtz(a, b);
  return z.h;
#else
  half2_t h;
  h[0] = (_Float16)a;
  h[1] = (_Float16)b;
  return h;
#endif
}

__device__ __forceinline__ half2_t as_h2(unsigned u) {
  union { unsigned u; half2_t h; } z;
  z.u = u;
  return z.h;
}

__device__ __forceinline__ f16x8 as_f16x8(uint4 u) {
  union { uint4 u; f16x8 f; } z;
  z.u = u;
  return z.f;
}

__device__ __forceinline__ float fdot2_(half2_t a, half2_t b, float c) {
#if __has_builtin(__builtin_amdgcn_fdot2)
  return __builtin_amdgcn_fdot2(a, b, c, false);
#else
  return c + (float)a[0] * (float)b[0] + (float)a[1] * (float)b[1];
#endif
}

// Guarded border-row load: returns the 4-tap row as an SSA value (no array).
__device__ __forceinline__ f32x4u brow(const float* __restrict__ xb, int iy,
                                       int ix0) {
  f32x4u r = {0.f, 0.f, 0.f, 0.f};
  if ((unsigned)iy < 112u) {
    const float* p = xb + iy * 112;
    r.x = ((unsigned)(ix0 + 0) < 112u) ? p[ix0 + 0] : 0.f;
    r.y = ((unsigned)(ix0 + 1) < 112u) ? p[ix0 + 1] : 0.f;
    r.z = ((unsigned)(ix0 + 2) < 112u) ? p[ix0 + 2] : 0.f;
    r.w = ((unsigned)(ix0 + 3) < 112u) ? p[ix0 + 3] : 0.f;
  }
  return r;
}

// conv1 8ch on a 4x4 window (rows r0..r3 BY VALUE -> registers, no scratch),
// 2x2 maxpool + bias + relu, packed to one uint4 (8 f16).
// wpl = LDS table of w1 tap-pairs (taps 0,1 per row), [ch*3+t].
__device__ __forceinline__ uint4 conv8v(f32x4u r0, f32x4u r1, f32x4u r2,
                                        f32x4u r3, const unsigned* wpl,
                                        const float* __restrict__ w1,
                                        const float* __restrict__ b1) {
  half2_t a0 = pkrtz2(r0.x, r0.y), c0 = pkrtz2(r0.y, r0.z);
  half2_t a1 = pkrtz2(r1.x, r1.y), c1 = pkrtz2(r1.y, r1.z);
  half2_t a2 = pkrtz2(r2.x, r2.y), c2 = pkrtz2(r2.y, r2.z);
  half2_t a3 = pkrtz2(r3.x, r3.y), c3 = pkrtz2(r3.y, r3.z);
  uint4 hw;
#pragma unroll
  for (int cp = 0; cp < 4; ++cp) {
    float hA = 0.f, hB = 0.f;
#pragma unroll
    for (int sub = 0; sub < 2; ++sub) {
      const int ch = 2 * cp + sub;
      half2_t w0 = as_h2(wpl[ch * 3 + 0]);
      half2_t w1p = as_h2(wpl[ch * 3 + 1]);
      half2_t w2p = as_h2(wpl[ch * 3 + 2]);
      float t0 = w1[ch * 9 + 2], t1 = w1[ch * 9 + 5], t2 = w1[ch * 9 + 8];
      float s00 = fdot2_(a2, w2p, fdot2_(a1, w1p, fdot2_(a0, w0, 0.f)));
      s00 = __builtin_fmaf(t0, r0.z, s00);
      s00 = __builtin_fmaf(t1, r1.z, s00);
      s00 = __builtin_fmaf(t2, r2.z, s00);
      float s01 = fdot2_(c2, w2p, fdot2_(c1, w1p, fdot2_(c0, w0, 0.f)));
      s01 = __builtin_fmaf(t0, r0.w, s01);
      s01 = __builtin_fmaf(t1, r1.w, s01);
      s01 = __builtin_fmaf(t2, r2.w, s01);
      float s10 = fdot2_(a3, w2p, fdot2_(a2, w1p, fdot2_(a1, w0, 0.f)));
      s10 = __builtin_fmaf(t0, r1.z, s10);
      s10 = __builtin_fmaf(t1, r2.z, s10);
      s10 = __builtin_fmaf(t2, r3.z, s10);
      float s11 = fdot2_(c3, w2p, fdot2_(c2, w1p, fdot2_(c1, w0, 0.f)));
      s11 = __builtin_fmaf(t0, r1.w, s11);
      s11 = __builtin_fmaf(t1, r2.w, s11);
      s11 = __builtin_fmaf(t2, r3.w, s11);
      float m = fmaxf(fmaxf(s00, s01), fmaxf(s10, s11));
      float h = fmaxf(m + b1[ch], 0.f);
      if (sub == 0) hA = h; else hB = h;
    }
    unsigned pk = pack_f16(hA, hB);
    if (cp == 0) hw.x = pk;
    else if (cp == 1) hw.y = pk;
    else if (cp == 2) hw.z = pk;
    else hw.w = pk;
  }
  return hw;
}

__global__ __launch_bounds__(1024, 8) void k_all(
    const float* __restrict__ x, const float* __restrict__ w1,
    const float* __restrict__ b1, const float* __restrict__ w2,
    const float* __restrict__ b2, const float* __restrict__ wp,
    const float* __restrict__ bp, const float* __restrict__ w_fc1,
    const float* __restrict__ b_fc1, const float* __restrict__ w_fc2,
    const float* __restrict__ b_fc2, float* __restrict__ out) {
  // hsu: [hr 0..57][hc 0..57][ch 0..7] f16; hr = pooled_row+1 (ring = zero)
  __shared__ __align__(16) unsigned hsu[HS * HS * 4];  // 53.8 KB
  __shared__ __align__(16) unsigned bwl[768];          // 3.0 KB [oc16][tap12][w4]
  __shared__ __align__(16) unsigned wpl[24];           // conv1 w-pairs [ch*3+t]
  __shared__ __align__(16) unsigned fsu[122 * FSW];    // 17.6 KB f16 K-major
  __shared__ __align__(16) float pfl[784];             // 3.1 KB
  __shared__ float h1s[64];
  const int tid = threadIdx.x;
  const int b = blockIdx.x;
  const int l = tid & 63;
  const int wv = __builtin_amdgcn_readfirstlane(tid >> 6);  // wave id 0..15
  const float* xb = x + (long)b * 12544;

  // ---- setup ----
  if (tid < 228) {  // zero the padding ring (P1 writes interior only)
    int i = tid, hr, hc;
    if (i < 58) { hr = 0; hc = i; }
    else if (i < 116) { hr = 57; hc = i - 58; }
    else if (i < 172) { hr = i - 115; hc = 0; }
    else { hr = i - 171; hc = 57; }
    *(uint4*)(hsu + (hr * HS + hc) * 4) = make_uint4(0u, 0u, 0u, 0u);
  }
  if (tid < 768) {  // conv2 weights: bwl[(oc*12+tap)*4+w]
    int t = tid, oc = t / 48, rem = t - oc * 48;
    int tap = rem >> 2, w = rem & 3;
    unsigned v = 0u;
    if (tap < 9)
      v = pack_f16(w2[(oc * 8 + 2 * w) * 9 + tap],
                   w2[(oc * 8 + 2 * w + 1) * 9 + tap]);
    bwl[t] = v;
  }
  if (tid >= 768 && tid < 792) {  // conv1 weight pairs (taps 0,1 per row)
    int t2 = tid - 768;
    int ch = t2 / 3, t = t2 - ch * 3;
    wpl[t2] = pack_f16(w1[ch * 9 + t * 3], w1[ch * 9 + t * 3 + 1]);
  }
  __syncthreads();  // BARRIER 0 — P1 reads wpl (R28 raced without this)

  // ---- P1: conv1+bias+relu+maxpool2 -> f16 pixel-major LDS tile ----
  // Interior (54x54): dense enumeration, all values SSA (no scratch).
  for (int t = tid; t < 2916; t += 1024) {
    int gr = 1 + t / 54, gc = 1 + t % 54;  // pooled coords, interior only
    const float* xp = xb + (2 * gr - 1) * 112 + (2 * gc - 1);
    f32x4u r0 = *(const f32x4u*)(xp);
    f32x4u r1 = *(const f32x4u*)(xp + 112);
    f32x4u r2 = *(const f32x4u*)(xp + 224);
    f32x4u r3 = *(const f32x4u*)(xp + 336);
    uint4 hw = conv8v(r0, r1, r2, r3, wpl, w1, b1);
    *(uint4*)(hsu + ((gr + 1) * HS + gc + 1) * 4) = hw;
  }
  // Border ring (220 pixels): tids 804..1023, guarded row builds (SSA).
  if (tid >= 804) {
    int i = tid - 804;  // 0..219
    int gr, gc;
    if (i < 56) { gr = 0; gc = i; }
    else if (i < 112) { gr = 55; gc = i - 56; }
    else if (i < 166) { gr = i - 111; gc = 0; }
    else { gr = i - 165; gc = 55; }
    int iy0 = 2 * gr - 1, ix0 = 2 * gc - 1;
    f32x4u r0 = brow(xb, iy0 + 0, ix0);
    f32x4u r1 = brow(xb, iy0 + 1, ix0);
    f32x4u r2 = brow(xb, iy0 + 2, ix0);
    f32x4u r3 = brow(xb, iy0 + 3, ix0);
    uint4 hw = conv8v(r0, r1, r2, r3, wpl, w1, b1);
    *(uint4*)(hsu + ((gr + 1) * HS + gc + 1) * 4) = hw;
  }
  __syncthreads();  // BARRIER 1

  // ---- P2: conv2+pool+relu via MFMA; wave-local (R24 verbatim) ----
  {
    const int q = l >> 4;       // k-quarter / f-pixel role (a=q>>1, b=q&1)
    const int oc = l & 15;      // also: patch-row-in-window for projection
    const int yoff = 2 * ((l >> 3) & 1) + ((l >> 1) & 1);  // 2a+dy
    const int xoff = 2 * ((l >> 2) & 1) + (l & 1);         // 2b+dx
    int poff[3];
#pragma unroll
    for (int kk = 0; kk < 3; ++kk) {
      int t = kk * 4 + q;
      int tt = t < 9 ? t : 8;  // dead taps alias tap 8 (B there is zero)
      int ty = tt / 3, tx = tt - ty * 3;
      poff[kk] = ((yoff + ty) * HS + xoff + tx) * 4;  // u32 units
    }
    uint4 bu0 = *(const uint4*)(bwl + (oc * 12 + 0 + q) * 4);
    uint4 bu1 = *(const uint4*)(bwl + (oc * 12 + 4 + q) * 4);
    uint4 bu2 = *(const uint4*)(bwl + (oc * 12 + 8 + q) * 4);
    const float b2v = b2[oc];

    // Projection B-frags: MFMA#1 wp[oc][q*8+j]; MFMA#2 wp[oc][32+q*8+j].
    f16x8 wpf0 = {}, wpf1 = {};
    float bpj = 0.f;
    if (oc < 4) {
      const float* wr = wp + oc * 64 + q * 8;
      float4 wa = *(const float4*)(wr);
      float4 wb = *(const float4*)(wr + 4);
      float4 wc = *(const float4*)(wr + 32);
      float4 wd = *(const float4*)(wr + 36);
      union { unsigned u[4]; f16x8 v; } u0, u1;
      u0.u[0] = pack_f16(wa.x, wa.y);
      u0.u[1] = pack_f16(wa.z, wa.w);
      u0.u[2] = pack_f16(wb.x, wb.y);
      u0.u[3] = pack_f16(wb.z, wb.w);
      u1.u[0] = pack_f16(wc.x, wc.y);
      u1.u[1] = pack_f16(wc.z, wc.w);
      u1.u[2] = pack_f16(wd.x, wd.y);
      u1.u[3] = pack_f16(wd.z, wd.w);
      wpf0 = u0.v;
      wpf1 = u1.v;
      bpj = bp[oc];
    }

    _Float16* fsh = (_Float16*)fsu;
    const int NP = (wv < 4) ? 13 : 12;              // patches owned (contig)
    const int G0 = (wv < 4) ? 13 * wv : 12 * wv + 4;
    const int RW = 7 * wv;                          // private fsu row base
    const int npA = (NP + 1) >> 1;

    for (int hlf = 0; hlf < 2; ++hlf) {
      const int np = hlf ? NP - npA : npA;          // 7|6 then 6
      const int g0 = hlf ? G0 + npA : G0;
      for (int i = 0; i < np; ++i) {
        int p = g0 + i;
        int py = p / 14, px = p - py * 14;
        int pb = (4 * py * HS + 4 * px) * 4;  // u32 offset of patch origin
        uint4 a0u = *(const uint4*)(hsu + pb + poff[0]);
        uint4 a1u = *(const uint4*)(hsu + pb + poff[1]);
        uint4 a2u = *(const uint4*)(hsu + pb + poff[2]);
        f32x4 acc = {0.f, 0.f, 0.f, 0.f};
        acc = __builtin_amdgcn_mfma_f32_16x16x32_f16(as_f16x8(a0u), as_f16x8(bu0), acc, 0, 0, 0);
        acc = __builtin_amdgcn_mfma_f32_16x16x32_f16(as_f16x8(a1u), as_f16x8(bu1), acc, 0, 0, 0);
        acc = __builtin_amdgcn_mfma_f32_16x16x32_f16(as_f16x8(a2u), as_f16x8(bu2), acc, 0, 0, 0);
        float mx = fmaxf(fmaxf(acc[0], acc[1]), fmaxf(acc[2], acc[3]));
        float fv = fmaxf(mx + b2v, 0.f);  // f[oc][f-pixel q] of patch p
        fsh[(RW + i) * FS + oc * 4 + q] = (_Float16)fv;
      }
      // FENCE: writes via _Float16*, reads via unsigned* (TBAA no-alias).
      asm volatile("s_waitcnt lgkmcnt(0)" ::: "memory");
      __builtin_amdgcn_sched_barrier(0);
      const unsigned* ar = fsu + (RW + oc) * FSW + q * 4;
      uint4 pa0 = *(const uint4*)(ar);        // k 0..31 slice
      uint4 pa1 = *(const uint4*)(ar + 16);   // k 32..63 slice
      f32x4 pc = {0.f, 0.f, 0.f, 0.f};
      pc = __builtin_amdgcn_mfma_f32_16x16x32_f16(as_f16x8(pa0), wpf0, pc, 0, 0, 0);
      pc = __builtin_amdgcn_mfma_f32_16x16x32_f16(as_f16x8(pa1), wpf1, pc, 0, 0, 0);
      if (oc < 4) {
#pragma unroll
        for (int i2 = 0; i2 < 4; ++i2) {
          int prow = q * 4 + i2;  // C row = patch within window
          if (prow < np) pfl[(g0 + prow) * 4 + oc] = pc[i2] + bpj;
        }
      }
      asm volatile("" ::: "memory");  // WAR: next half's writes stay below
    }
  }
  __syncthreads();  // BARRIER 2

  // ---- fc1: thread (j = tid>>4, q16 = tid&15); 16-way K-split ----
  {
    int j = tid >> 4, q16 = tid & 15;
    const float* wrow = w_fc1 + j * 784;
    float acc = 0.f;
    for (int lp = q16; lp < 196; lp += 16) {
      float4 w4 = *(const float4*)(wrow + lp * 4);
      float4 p4 = *(const float4*)(pfl + lp * 4);
      acc += w4.x * p4.x + w4.y * p4.y + w4.z * p4.z + w4.w * p4.w;
    }
    acc += __shfl_down(acc, 8, 16);
    acc += __shfl_down(acc, 4, 16);
    acc += __shfl_down(acc, 2, 16);
    acc += __shfl_down(acc, 1, 16);
    if (q16 == 0) h1s[j] = fmaxf(acc + b_fc1[j], 0.f);
  }
  __syncthreads();  // BARRIER 3

  // ---- fc2 + log_softmax: wave 0 only ----
  if (wv == 0) {
    float h = h1s[l];
    float lg[10];
#pragma unroll
    for (int o = 0; o < 10; ++o) {
      float t = h * w_fc2[o * 64 + l];
#pragma unroll
      for (int off = 32; off; off >>= 1) t += __shfl_xor(t, off);
      lg[o] = t + b_fc2[o];  // every lane holds all 10 logits
    }
    float mx = lg[0];
#pragma unroll
    for (int o = 1; o < 10; ++o) mx = fmaxf(mx, lg[o]);
    float se = 0.f;
#pragma unroll
    for (int o = 0; o < 10; ++o) se += __expf(lg[o] - mx);
    float ls = mx + __logf(se);
#pragma unroll
    for (int o = 0; o < 10; ++o)  // static-index stores (no scratch)
      if (l == o) out[b * 10 + o] = lg[o] - ls;
  }
}

extern "C" void kernel_launch(void* const* d_in, const int* in_sizes, int n_in,
                              void* d_out, int out_size, void* d_ws, size_t ws_size,
                              hipStream_t stream) {
  const float* x = (const float*)d_in[0];
  const float* w1 = (const float*)d_in[1];
  const float* b1 = (const float*)d_in[2];
  const float* w2 = (const float*)d_in[3];
  const float* b2 = (const float*)d_in[4];
  const float* wp = (const float*)d_in[5];
  const float* bp = (const float*)d_in[6];
  const float* wf1 = (const float*)d_in[7];
  const float* bf1 = (const float*)d_in[8];
  const float* wf2 = (const float*)d_in[9];
  const float* bf2 = (const float*)d_in[10];
  (void)d_ws; (void)ws_size;  // workspace unused

  k_all<<<dim3(512), 1024, 0, stream>>>(x, w1, b1, w2, b2, wp, bp, wf1, bf1,
                                        wf2, bf2, (float*)d_out);
}